// Round 1
// baseline (173.654 us; speedup 1.0000x reference)
//
#include <hip/hip_runtime.h>

// Forecaster: B=64, S=1024, F=64, H=128. N = B*S = 65536 independent instances.
// R12: overlap/lockstep attack. R11 counters: MfmaUtil 20%, VALUBusy 42%,
// bank-conflict 2.75M, 2wg/CU — ~38% of cycles are neither-pipe-busy
// (gemm-burst/epilogue-burst lockstep + barrier drain + LDS conflicts).
// Changes vs R11 (math identical):
//  1. H buffers stride 136->128 halfs with XOR swizzle (byte ^= (row&7)<<4)
//     on both write (8B, granule-safe) and read (16B): conflict-free ds ops,
//     LDS 70656 -> 49152.
//  2. A0 LDS staging dropped: S1 A-frags loaded direct from global x into
//     registers (same f32->f16 cast; 8-wave redundancy absorbed by L1).
//  3. 1-tile wgs (grid 1024): no tile loop, inter-wg phase diversity fills
//     barrier drains; heavy "+v" laundering replaced by per-stage "+s" fences.
//  4. S2-epi interleaved per-mt with S3-gemm slices (both between the same
//     barriers, independent): explicit VALU||MFMA overlap, acc reused per mt.
//     S3 bq re-read per mt: +~0.4GB L2 traffic, still far under L2 BW.
//  5. s_setprio(1) around MFMA clusters (T5; cross-wg diversity now exists).
//  6. __launch_bounds__(512,4) guards the >128-VGPR occupancy cliff.
// Lessons kept: R4 no min-waves clamp beyond 4; R6 mt=4 weight amortization
// (bq transient per kc where acc pressure allows); R8-R10 pointer fences.

typedef _Float16 half8 __attribute__((ext_vector_type(8)));
typedef _Float16 half4_t __attribute__((ext_vector_type(4)));
typedef float f32x4 __attribute__((ext_vector_type(4)));

#define L2E  1.4426950408889634f
#define L2E2 2.8853900817779268f

#define WP_WIH0 0
#define WP_WHH0 32768
#define WP_WIH1 98304
#define WP_WHH1 163840
#define WS_BIAS0 458752            // bytes
#define WS_BIAS1 (458752 + 2048)
#define WS_MUG2  (458752 + 4096)

// ---------------- merged prep kernel (unchanged) ----------------------------
__global__ void prep_kernel(const float* __restrict__ Wih0,
                            const float* __restrict__ Whh0,
                            const float* __restrict__ Wih1,
                            const float* __restrict__ Whh1,
                            const float* __restrict__ bih0,
                            const float* __restrict__ bhh0,
                            const float* __restrict__ bih1,
                            const float* __restrict__ bhh1,
                            const float* __restrict__ mu,
                            _Float16* __restrict__ Wp,
                            float* __restrict__ bias0f,
                            float* __restrict__ bias1f,
                            float* __restrict__ mu_g2)
{
    int blk = blockIdx.x;
    if (blk >= 113) {                       // ---- mu_g2 part
        int o = (blk - 113) * 256 + threadIdx.x;   // 0..32767
        int b = o >> 9;
        int n = o & 511;
        float s = bih0[n] + bhh0[n];
        const float* m = mu + b * 64;
        const float* wrow = Wih0 + n * 64;
        #pragma unroll 8
        for (int k = 0; k < 64; ++k) s += m[k] * wrow[k];
        float scale = ((n >> 7) == 2) ? L2E2 : L2E;
        mu_g2[o] = s * scale;
        return;
    }
    if (blk == 112) {                       // ---- bias part
        int i = threadIdx.x;
        float sc_hi = (i < 128) ? L2E2 : L2E;
        bias0f[i]       = (bih0[i]       + bhh0[i])       * L2E;
        bias0f[i + 256] = (bih0[i + 256] + bhh0[i + 256]) * sc_hi;
        bias1f[i]       = (bih1[i]       + bhh1[i])       * L2E;
        bias1f[i + 256] = (bih1[i + 256] + bhh1[i + 256]) * sc_hi;
        return;
    }
    // ---- weight pack: [nt][kc][lane][8], c=lane&15 -> n=nt*16+c,
    //      q=lane>>4 -> k = kc*32 + q*8 .. +8  (scaled by gate)
    int gidx = blk * 256 + threadIdx.x;     // 0..28671 groups of 8 halfs
    const float* src; int KC, Kw, local;
    if (gidx < 4096)       { src = Wih0; KC = 2; Kw = 64;  local = gidx; }
    else if (gidx < 12288) { src = Whh0; KC = 4; Kw = 128; local = gidx - 4096; }
    else if (gidx < 20480) { src = Wih1; KC = 4; Kw = 128; local = gidx - 12288; }
    else                   { src = Whh1; KC = 4; Kw = 128; local = gidx - 20480; }
    int lane = local & 63;
    int tmp  = local >> 6;
    int kc   = tmp % KC;
    int nt   = tmp / KC;
    int n  = nt * 16 + (lane & 15);
    int k0 = kc * 32 + (lane >> 4) * 8;
    float scale = ((n >> 7) == 2) ? L2E2 : L2E;
    const float* s = src + n * Kw + k0;
    half8 hv;
    #pragma unroll
    for (int j = 0; j < 8; ++j) hv[j] = (_Float16)(s[j] * scale);
    *(half8*)(Wp + (size_t)gidx * 8) = hv;
}

// ---------------- bare-metal gate math -------------------------------------
__device__ __forceinline__ float sig2(float a) {
    return __builtin_amdgcn_rcpf(1.0f + __builtin_amdgcn_exp2f(-a));
}
__device__ __forceinline__ float tanh2(float a) {
    return fmaf(-2.0f, __builtin_amdgcn_rcpf(1.0f + __builtin_amdgcn_exp2f(a)), 1.0f);
}

// Swizzled byte offset into a [64 rows][256B] H tile. col < 256; the XOR term
// (row&7)<<4 < 128 touches only bits 4..6 -> no carry into row bits; 16B
// granules move, 8B/16B intra-granule alignment preserved. Same involution
// on write and read (rule #21).
__device__ __forceinline__ int swz(int row, int col) {
    return (row << 8) + (col ^ ((row & 7) << 4));
}

template<int KC>
__device__ __forceinline__ void gemm_lds(const _Float16* __restrict__ Wq,
                                         const char* Hb,
                                         int w, int lane, f32x4 acc[4][4])
{
    const int c = lane & 15, q = lane >> 4;
    #pragma unroll
    for (int kc = 0; kc < KC; ++kc) {
        half8 a[4], bq[4];
        #pragma unroll
        for (int mt = 0; mt < 4; ++mt)
            a[mt] = *(const half8*)(Hb + swz(mt * 16 + c, kc * 64 + q * 16));
        #pragma unroll
        for (int g = 0; g < 4; ++g)
            bq[g] = *(const half8*)(Wq + (((g * 8 + w) * KC + kc) * 64 + lane) * 8);
        // operand swap: A:=weight, B:=batch -> D[row->hidden, col->batch]
        #pragma unroll
        for (int mt = 0; mt < 4; ++mt)
            #pragma unroll
            for (int g = 0; g < 4; ++g)
                acc[mt][g] = __builtin_amdgcn_mfma_f32_16x16x32_f16(bq[g], a[mt], acc[mt][g], 0, 0, 0);
    }
}

__global__ __launch_bounds__(512, 4) void lstm_main(
    const float* __restrict__ x, const _Float16* __restrict__ Wp_in,
    const float* __restrict__ bias0f_in, const float* __restrict__ bias1f_in,
    const float* __restrict__ mu_g2_in, const float* __restrict__ fc_w_in,
    const float* __restrict__ fc_b_in, float* __restrict__ out)
{
    // LDS 49152 B, swizzled stride-128 tiles:
    //  [0, 16384)       H1s
    //  [16384, 32768)   H2s
    //  [32768, 49152)   H11s
    __shared__ __align__(16) char smem[49152];
    char* H1s  = smem;
    char* H2s  = smem + 16384;
    char* H11s = smem + 32768;

    const int t = threadIdx.x;
    const int w = t >> 6, lane = t & 63, c = lane & 15, q = lane >> 4;
    const int wg = blockIdx.x;                   // 1024 wgs x 64 rows
    const int b = wg >> 4;                       // 16 wgs (1024 rows) per batch
    const int bq_idx = w * 4 + q;                // float4 index of (w,q) slice

    // ---- preamble: S1 A-frags direct from global x; init out rows ---------
    half8 ax[8];                                 // [mt][kc], 16 VGPRs
    {
        const float* xb = x + (size_t)wg * 4096;
        #pragma unroll
        for (int mt = 0; mt < 4; ++mt)
            #pragma unroll
            for (int kc = 0; kc < 2; ++kc) {
                const float* p = xb + (mt * 16 + c) * 64 + kc * 32 + q * 8;
                float4 u0 = ((const float4*)p)[0];
                float4 u1 = ((const float4*)p)[1];
                half8 hv;
                hv[0] = (_Float16)u0.x; hv[1] = (_Float16)u0.y;
                hv[2] = (_Float16)u0.z; hv[3] = (_Float16)u0.w;
                hv[4] = (_Float16)u1.x; hv[5] = (_Float16)u1.y;
                hv[6] = (_Float16)u1.z; hv[7] = (_Float16)u1.w;
                ax[mt * 2 + kc] = hv;
            }
        if (t < 64) out[(size_t)wg * 64 + t] = fc_b_in[0];
    }

    f32x4 acc[4][4];
    float cc[4][4];

    // ---- S1: layer0 step1 (A from registers, no LDS source) ---------------
    {
        const float* bias0f = bias0f_in; asm volatile("" : "+s"(bias0f));
        #pragma unroll
        for (int g = 0; g < 4; ++g) {
            f32x4 bv = ((const f32x4*)bias0f)[g * 32 + bq_idx];
            #pragma unroll
            for (int mt = 0; mt < 4; ++mt) acc[mt][g] = bv;
        }
    }
    {
        const _Float16* W0 = Wp_in + WP_WIH0; asm volatile("" : "+s"(W0));
        __builtin_amdgcn_s_setprio(1);
        #pragma unroll
        for (int kc = 0; kc < 2; ++kc) {
            half8 bq[4];
            #pragma unroll
            for (int g = 0; g < 4; ++g)
                bq[g] = *(const half8*)(W0 + (((g * 8 + w) * 2 + kc) * 64 + lane) * 8);
            #pragma unroll
            for (int mt = 0; mt < 4; ++mt)
                #pragma unroll
                for (int g = 0; g < 4; ++g)
                    acc[mt][g] = __builtin_amdgcn_mfma_f32_16x16x32_f16(bq[g], ax[mt * 2 + kc], acc[mt][g], 0, 0, 0);
        }
        __builtin_amdgcn_s_setprio(0);
    }
    #pragma unroll
    for (int mt = 0; mt < 4; ++mt) {
        half4_t hv;
        #pragma unroll
        for (int r = 0; r < 4; ++r) {
            float c1 = sig2(acc[mt][0][r]) * tanh2(acc[mt][2][r]);
            cc[mt][r] = c1;
            hv[r] = (_Float16)(sig2(acc[mt][3][r]) * tanh2(c1 * L2E2));
        }
        *(half4_t*)(H1s + swz(mt * 16 + c, w * 32 + q * 8)) = hv;
    }
    __syncthreads();   // [S1-barrier] H1s ready; out-init drained (vmcnt 0)

    // ---- S2: layer0 step2 gemm (reads H1s) --------------------------------
    {
        const float* mu_g2b = mu_g2_in + b * 512; asm volatile("" : "+s"(mu_g2b));
        #pragma unroll
        for (int g = 0; g < 4; ++g) {
            f32x4 bv = ((const f32x4*)mu_g2b)[g * 32 + bq_idx];
            #pragma unroll
            for (int mt = 0; mt < 4; ++mt) acc[mt][g] = bv;
        }
    }
    {
        const _Float16* Wq = Wp_in + WP_WHH0; asm volatile("" : "+s"(Wq));
        __builtin_amdgcn_s_setprio(1);
        gemm_lds<4>(Wq, H1s, w, lane, acc);
        __builtin_amdgcn_s_setprio(0);
    }

    // bias1 fragment, reused by S3 slices and S4 init
    f32x4 bv1[4];
    {
        const float* bias1f = bias1f_in; asm volatile("" : "+s"(bias1f));
        #pragma unroll
        for (int g = 0; g < 4; ++g)
            bv1[g] = ((const f32x4*)bias1f)[g * 32 + bq_idx];
    }

    // ---- interleaved: S2-epilogue(mt) || S3-gemm-slice(mt) ----------------
    // Both live between S1-barrier and S3-barrier and are independent
    // (epi2 writes H2s, S3 reads H1s): per-mt slicing exposes VALU||MFMA
    // overlap to the scheduler; acc[mt] is drained by epi2 then re-inited.
    {
        const _Float16* Wih1p = Wp_in + WP_WIH1; asm volatile("" : "+s"(Wih1p));
        #pragma unroll
        for (int mt = 0; mt < 4; ++mt) {
            // epi2(mt): h2 -> H2s (cc keeps layer-0 c1; c2 is transient)
            half4_t hv;
            #pragma unroll
            for (int r = 0; r < 4; ++r) {
                float c2 = sig2(acc[mt][1][r]) * cc[mt][r]
                         + sig2(acc[mt][0][r]) * tanh2(acc[mt][2][r]);
                hv[r] = (_Float16)(sig2(acc[mt][3][r]) * tanh2(c2 * L2E2));
            }
            *(half4_t*)(H2s + swz(mt * 16 + c, w * 32 + q * 8)) = hv;
            // S3 slice(mt): layer1 step1 gemm over H1s rows of this mt
            #pragma unroll
            for (int g = 0; g < 4; ++g) acc[mt][g] = bv1[g];
            __builtin_amdgcn_s_setprio(1);
            #pragma unroll
            for (int kc = 0; kc < 4; ++kc) {
                half8 av = *(const half8*)(H1s + swz(mt * 16 + c, kc * 64 + q * 16));
                #pragma unroll
                for (int g = 0; g < 4; ++g) {
                    half8 bq = *(const half8*)(Wih1p + (((g * 8 + w) * 4 + kc) * 64 + lane) * 8);
                    acc[mt][g] = __builtin_amdgcn_mfma_f32_16x16x32_f16(bq, av, acc[mt][g], 0, 0, 0);
                }
            }
            __builtin_amdgcn_s_setprio(0);
        }
    }
    // epi3: h11 -> H11s, cc := layer-1 c1
    #pragma unroll
    for (int mt = 0; mt < 4; ++mt) {
        half4_t hv;
        #pragma unroll
        for (int r = 0; r < 4; ++r) {
            float c1 = sig2(acc[mt][0][r]) * tanh2(acc[mt][2][r]);
            cc[mt][r] = c1;
            hv[r] = (_Float16)(sig2(acc[mt][3][r]) * tanh2(c1 * L2E2));
        }
        *(half4_t*)(H11s + swz(mt * 16 + c, w * 32 + q * 8)) = hv;
    }
    __syncthreads();   // [S3-barrier] H2s + H11s ready

    // ---- S4: layer1 step2 --------------------------------------------------
    #pragma unroll
    for (int g = 0; g < 4; ++g)
        #pragma unroll
        for (int mt = 0; mt < 4; ++mt) acc[mt][g] = bv1[g];
    {
        const _Float16* Wa = Wp_in + WP_WIH1; asm volatile("" : "+s"(Wa));
        const _Float16* Wb = Wp_in + WP_WHH1; asm volatile("" : "+s"(Wb));
        __builtin_amdgcn_s_setprio(1);
        gemm_lds<4>(Wa, H2s,  w, lane, acc);
        gemm_lds<4>(Wb, H11s, w, lane, acc);
        __builtin_amdgcn_s_setprio(0);
    }
    // epilogue: h2_1 -> relu -> dot fc_w; partials straight to L2 atomics
    // (out pre-inited with fc_b in preamble; only this wg touches these 64
    //  rows; init/atomic ordering guaranteed by the two barriers above).
    {
        const float* fc_w = fc_w_in; asm volatile("" : "+s"(fc_w));
        f32x4 fwv = ((const f32x4*)fc_w)[bq_idx];
        #pragma unroll
        for (int mt = 0; mt < 4; ++mt) {
            float v = 0.0f;
            #pragma unroll
            for (int r = 0; r < 4; ++r) {
                float c2 = sig2(acc[mt][1][r]) * cc[mt][r]
                         + sig2(acc[mt][0][r]) * tanh2(acc[mt][2][r]);
                float h  = sig2(acc[mt][3][r]) * tanh2(c2 * L2E2);
                v = fmaf(fmaxf(h, 0.0f), fwv[r], v);
            }
            v += __shfl_xor(v, 16);
            v += __shfl_xor(v, 32);
            if (lane < 16)
                atomicAdd(out + (size_t)wg * 64 + mt * 16 + lane, v);
        }
    }
}

extern "C" void kernel_launch(void* const* d_in, const int* in_sizes, int n_in,
                              void* d_out, int out_size, void* d_ws, size_t ws_size,
                              hipStream_t stream)
{
    const float* x    = (const float*)d_in[0];
    const float* mu   = (const float*)d_in[1];
    const float* Wih0 = (const float*)d_in[2];
    const float* Whh0 = (const float*)d_in[3];
    const float* bih0 = (const float*)d_in[4];
    const float* bhh0 = (const float*)d_in[5];
    const float* Wih1 = (const float*)d_in[6];
    const float* Whh1 = (const float*)d_in[7];
    const float* bih1 = (const float*)d_in[8];
    const float* bhh1 = (const float*)d_in[9];
    const float* fcw  = (const float*)d_in[10];
    const float* fcb  = (const float*)d_in[11];
    float* out = (float*)d_out;

    _Float16* Wp  = (_Float16*)d_ws;
    float* bias0f = (float*)((char*)d_ws + WS_BIAS0);
    float* bias1f = (float*)((char*)d_ws + WS_BIAS1);
    float* mu_g2  = (float*)((char*)d_ws + WS_MUG2);

    hipLaunchKernelGGL(prep_kernel, dim3(241), dim3(256), 0, stream,
                       Wih0, Whh0, Wih1, Whh1, bih0, bhh0, bih1, bhh1, mu,
                       Wp, bias0f, bias1f, mu_g2);
    hipLaunchKernelGGL(lstm_main, dim3(1024), dim3(512), 0, stream,
                       x, Wp, bias0f, bias1f, mu_g2, fcw, fcb, out);
}

// Round 2
// 144.748 us; speedup vs baseline: 1.1997x; 1.1997x over previous
//
#include <hip/hip_runtime.h>

// Forecaster: B=64, S=1024, F=64, H=128. N = B*S = 65536 independent instances.
// R13: revert R12's spill disaster, keep its good ideas un-spilled.
// R12 post-mortem: __launch_bounds__(512,4) + ax/bv1 register demand (~150)
// -> VGPR clamped to 64, 100MB scratch spill (WRITE_SIZE 2.3->102 MB),
// 99us. Also: swizzle did NOT move SQ_LDS_BANK_CONFLICT (2.75M->2.49M) ->
// that counter is mostly NOT the H-tile access pattern (shfl/ds_permute
// suspected); swizzle kept only for the LDS-size win.
// R13 = R11 skeleton (69.4us, VGPR 100, no spill) with:
//  1. plain __launch_bounds__(512)  [R4 lesson re-learned: no min-waves]
//  2. LDS A0 staging kept (coalesced; no 32-VGPR ax array)
//  3. 1-tile wgs, grid 1024: wg churn decorrelates barrier phases, halves
//     tail; single A0 buffer; LDS 58368 B -> 2 wg/CU.
//  4. swizzled stride-128 H tiles + s_setprio around MFMA clusters.
//  5. S2-epi(mt) || S3-gemm(mt) interleave (the overlap lever R12 never
//     actually tested): peak live ~115 VGPR < 128.
// Lessons kept: R6 mt=4 weight amortization; R8-R10 pointer fences (light
// "+s" per stage to stop whole-kernel hoisting of pointers/bias loads).

typedef _Float16 half8 __attribute__((ext_vector_type(8)));
typedef _Float16 half4_t __attribute__((ext_vector_type(4)));
typedef float f32x4 __attribute__((ext_vector_type(4)));

#define L2E  1.4426950408889634f
#define L2E2 2.8853900817779268f

#define WP_WIH0 0
#define WP_WHH0 32768
#define WP_WIH1 98304
#define WP_WHH1 163840
#define WS_BIAS0 458752            // bytes
#define WS_BIAS1 (458752 + 2048)
#define WS_MUG2  (458752 + 4096)

// ---------------- merged prep kernel (unchanged) ----------------------------
__global__ void prep_kernel(const float* __restrict__ Wih0,
                            const float* __restrict__ Whh0,
                            const float* __restrict__ Wih1,
                            const float* __restrict__ Whh1,
                            const float* __restrict__ bih0,
                            const float* __restrict__ bhh0,
                            const float* __restrict__ bih1,
                            const float* __restrict__ bhh1,
                            const float* __restrict__ mu,
                            _Float16* __restrict__ Wp,
                            float* __restrict__ bias0f,
                            float* __restrict__ bias1f,
                            float* __restrict__ mu_g2)
{
    int blk = blockIdx.x;
    if (blk >= 113) {                       // ---- mu_g2 part
        int o = (blk - 113) * 256 + threadIdx.x;   // 0..32767
        int b = o >> 9;
        int n = o & 511;
        float s = bih0[n] + bhh0[n];
        const float* m = mu + b * 64;
        const float* wrow = Wih0 + n * 64;
        #pragma unroll 8
        for (int k = 0; k < 64; ++k) s += m[k] * wrow[k];
        float scale = ((n >> 7) == 2) ? L2E2 : L2E;
        mu_g2[o] = s * scale;
        return;
    }
    if (blk == 112) {                       // ---- bias part
        int i = threadIdx.x;
        float sc_hi = (i < 128) ? L2E2 : L2E;
        bias0f[i]       = (bih0[i]       + bhh0[i])       * L2E;
        bias0f[i + 256] = (bih0[i + 256] + bhh0[i + 256]) * sc_hi;
        bias1f[i]       = (bih1[i]       + bhh1[i])       * L2E;
        bias1f[i + 256] = (bih1[i + 256] + bhh1[i + 256]) * sc_hi;
        return;
    }
    // ---- weight pack: [nt][kc][lane][8], c=lane&15 -> n=nt*16+c,
    //      q=lane>>4 -> k = kc*32 + q*8 .. +8  (scaled by gate)
    int gidx = blk * 256 + threadIdx.x;     // 0..28671 groups of 8 halfs
    const float* src; int KC, Kw, local;
    if (gidx < 4096)       { src = Wih0; KC = 2; Kw = 64;  local = gidx; }
    else if (gidx < 12288) { src = Whh0; KC = 4; Kw = 128; local = gidx - 4096; }
    else if (gidx < 20480) { src = Wih1; KC = 4; Kw = 128; local = gidx - 12288; }
    else                   { src = Whh1; KC = 4; Kw = 128; local = gidx - 20480; }
    int lane = local & 63;
    int tmp  = local >> 6;
    int kc   = tmp % KC;
    int nt   = tmp / KC;
    int n  = nt * 16 + (lane & 15);
    int k0 = kc * 32 + (lane >> 4) * 8;
    float scale = ((n >> 7) == 2) ? L2E2 : L2E;
    const float* s = src + n * Kw + k0;
    half8 hv;
    #pragma unroll
    for (int j = 0; j < 8; ++j) hv[j] = (_Float16)(s[j] * scale);
    *(half8*)(Wp + (size_t)gidx * 8) = hv;
}

// ---------------- bare-metal gate math -------------------------------------
__device__ __forceinline__ float sig2(float a) {
    return __builtin_amdgcn_rcpf(1.0f + __builtin_amdgcn_exp2f(-a));
}
__device__ __forceinline__ float tanh2(float a) {
    return fmaf(-2.0f, __builtin_amdgcn_rcpf(1.0f + __builtin_amdgcn_exp2f(a)), 1.0f);
}

// Swizzled byte offset into a [64 rows][256B] H tile. XOR term (row&7)<<4
// touches only bits 4..6 (no carry into row bits); 16B granules move, 8B/16B
// alignment preserved; same involution on write and read (rule #21).
__device__ __forceinline__ int swz(int row, int col) {
    return (row << 8) + (col ^ ((row & 7) << 4));
}

// A from plain strided LDS (A0 staging buffer, stride 72 halfs)
template<int KC>
__device__ __forceinline__ void gemm_stage(const _Float16* __restrict__ Wq,
                                           const _Float16* A, const int strideA,
                                           int w, int lane, f32x4 acc[4][4])
{
    const int c = lane & 15, q = lane >> 4;
    #pragma unroll
    for (int kc = 0; kc < KC; ++kc) {
        half8 a[4], bq[4];
        #pragma unroll
        for (int mt = 0; mt < 4; ++mt)
            a[mt] = *(const half8*)(A + (mt * 16 + c) * strideA + kc * 32 + q * 8);
        #pragma unroll
        for (int g = 0; g < 4; ++g)
            bq[g] = *(const half8*)(Wq + (((g * 8 + w) * KC + kc) * 64 + lane) * 8);
        // operand swap: A:=weight, B:=batch -> D[row->hidden, col->batch]
        #pragma unroll
        for (int mt = 0; mt < 4; ++mt)
            #pragma unroll
            for (int g = 0; g < 4; ++g)
                acc[mt][g] = __builtin_amdgcn_mfma_f32_16x16x32_f16(bq[g], a[mt], acc[mt][g], 0, 0, 0);
    }
}

// A from swizzled H tile
template<int KC>
__device__ __forceinline__ void gemm_lds(const _Float16* __restrict__ Wq,
                                         const char* Hb,
                                         int w, int lane, f32x4 acc[4][4])
{
    const int c = lane & 15, q = lane >> 4;
    #pragma unroll
    for (int kc = 0; kc < KC; ++kc) {
        half8 a[4], bq[4];
        #pragma unroll
        for (int mt = 0; mt < 4; ++mt)
            a[mt] = *(const half8*)(Hb + swz(mt * 16 + c, kc * 64 + q * 16));
        #pragma unroll
        for (int g = 0; g < 4; ++g)
            bq[g] = *(const half8*)(Wq + (((g * 8 + w) * KC + kc) * 64 + lane) * 8);
        #pragma unroll
        for (int mt = 0; mt < 4; ++mt)
            #pragma unroll
            for (int g = 0; g < 4; ++g)
                acc[mt][g] = __builtin_amdgcn_mfma_f32_16x16x32_f16(bq[g], a[mt], acc[mt][g], 0, 0, 0);
    }
}

__global__ __launch_bounds__(512) void lstm_main(
    const float* __restrict__ x, const _Float16* __restrict__ Wp_in,
    const float* __restrict__ bias0f_in, const float* __restrict__ bias1f_in,
    const float* __restrict__ mu_g2_in, const float* __restrict__ fc_w_in,
    const float* __restrict__ fc_b_in, float* __restrict__ out)
{
    // LDS 58368 B (2 wg/CU = 116.7 KB <= 160):
    //  [0, 16384)       H1s   (swizzled [64][256B])
    //  [16384, 32768)   H2s
    //  [32768, 49152)   H11s
    //  [49152, 58368)   A0    (64 x 72 halfs, coalesced staging)
    __shared__ __align__(16) char smem[58368];
    char* H1s  = smem;
    char* H2s  = smem + 16384;
    char* H11s = smem + 32768;
    _Float16* A0 = (_Float16*)(smem + 49152);

    const int t = threadIdx.x;
    const int w = t >> 6, lane = t & 63, c = lane & 15, q = lane >> 4;
    const int wg = blockIdx.x;                   // 1024 wgs x 64 rows
    const int b = wg >> 4;                       // 16 wgs (1024 rows) per batch
    const int bq_idx = w * 4 + q;                // float4 index of (w,q) slice

    // ---- preamble: stage x tile into A0 (coalesced); init out rows --------
    {
        const float* xp = x + (size_t)wg * 4096 + t * 8;
        float4 u0 = ((const float4*)xp)[0];
        float4 u1 = ((const float4*)xp)[1];
        half8 hv;
        hv[0] = (_Float16)u0.x; hv[1] = (_Float16)u0.y;
        hv[2] = (_Float16)u0.z; hv[3] = (_Float16)u0.w;
        hv[4] = (_Float16)u1.x; hv[5] = (_Float16)u1.y;
        hv[6] = (_Float16)u1.z; hv[7] = (_Float16)u1.w;
        *(half8*)(A0 + (t >> 3) * 72 + (t & 7) * 8) = hv;
        if (t < 64) out[(size_t)wg * 64 + t] = fc_b_in[0];
    }
    __syncthreads();   // A0 + out-init visible

    f32x4 acc[4][4];
    float cc[4][4];

    // ---- S1: layer0 step1 (reads A0) --------------------------------------
    {
        const float* bias0f = bias0f_in; asm volatile("" : "+s"(bias0f));
        #pragma unroll
        for (int g = 0; g < 4; ++g) {
            f32x4 bv = ((const f32x4*)bias0f)[g * 32 + bq_idx];
            #pragma unroll
            for (int mt = 0; mt < 4; ++mt) acc[mt][g] = bv;
        }
    }
    {
        const _Float16* W0 = Wp_in + WP_WIH0; asm volatile("" : "+s"(W0));
        __builtin_amdgcn_s_setprio(1);
        gemm_stage<2>(W0, A0, 72, w, lane, acc);
        __builtin_amdgcn_s_setprio(0);
    }
    #pragma unroll
    for (int mt = 0; mt < 4; ++mt) {
        half4_t hv;
        #pragma unroll
        for (int r = 0; r < 4; ++r) {
            float c1 = sig2(acc[mt][0][r]) * tanh2(acc[mt][2][r]);
            cc[mt][r] = c1;
            hv[r] = (_Float16)(sig2(acc[mt][3][r]) * tanh2(c1 * L2E2));
        }
        *(half4_t*)(H1s + swz(mt * 16 + c, w * 32 + q * 8)) = hv;
    }
    __syncthreads();   // [S1-barrier] H1s ready

    // ---- S2: layer0 step2 gemm (reads H1s) --------------------------------
    {
        const float* mu_g2b = mu_g2_in + b * 512; asm volatile("" : "+s"(mu_g2b));
        #pragma unroll
        for (int g = 0; g < 4; ++g) {
            f32x4 bv = ((const f32x4*)mu_g2b)[g * 32 + bq_idx];
            #pragma unroll
            for (int mt = 0; mt < 4; ++mt) acc[mt][g] = bv;
        }
    }
    {
        const _Float16* Wq = Wp_in + WP_WHH0; asm volatile("" : "+s"(Wq));
        __builtin_amdgcn_s_setprio(1);
        gemm_lds<4>(Wq, H1s, w, lane, acc);
        __builtin_amdgcn_s_setprio(0);
    }

    // bias1 fragment, reused by S3 slices and S4 init
    f32x4 bv1[4];
    {
        const float* bias1f = bias1f_in; asm volatile("" : "+s"(bias1f));
        #pragma unroll
        for (int g = 0; g < 4; ++g)
            bv1[g] = ((const f32x4*)bias1f)[g * 32 + bq_idx];
    }

    // ---- interleaved: S2-epilogue(mt) || S3-gemm-slice(mt) ----------------
    // Both live between S1-barrier and S3-barrier and are independent
    // (epi2 writes H2s, S3 reads H1s): per-mt slicing exposes VALU||MFMA
    // overlap to the scheduler; acc[mt] is drained by epi2 then re-inited.
    {
        const _Float16* Wih1p = Wp_in + WP_WIH1; asm volatile("" : "+s"(Wih1p));
        #pragma unroll
        for (int mt = 0; mt < 4; ++mt) {
            // epi2(mt): h2 -> H2s (cc keeps layer-0 c1; c2 is transient)
            half4_t hv;
            #pragma unroll
            for (int r = 0; r < 4; ++r) {
                float c2 = sig2(acc[mt][1][r]) * cc[mt][r]
                         + sig2(acc[mt][0][r]) * tanh2(acc[mt][2][r]);
                hv[r] = (_Float16)(sig2(acc[mt][3][r]) * tanh2(c2 * L2E2));
            }
            *(half4_t*)(H2s + swz(mt * 16 + c, w * 32 + q * 8)) = hv;
            // S3 slice(mt): layer1 step1 gemm over H1s rows of this mt
            #pragma unroll
            for (int g = 0; g < 4; ++g) acc[mt][g] = bv1[g];
            __builtin_amdgcn_s_setprio(1);
            #pragma unroll
            for (int kc = 0; kc < 4; ++kc) {
                half8 av = *(const half8*)(H1s + swz(mt * 16 + c, kc * 64 + q * 16));
                #pragma unroll
                for (int g = 0; g < 4; ++g) {
                    half8 bq = *(const half8*)(Wih1p + (((g * 8 + w) * 4 + kc) * 64 + lane) * 8);
                    acc[mt][g] = __builtin_amdgcn_mfma_f32_16x16x32_f16(bq, av, acc[mt][g], 0, 0, 0);
                }
            }
            __builtin_amdgcn_s_setprio(0);
        }
    }
    // epi3: h11 -> H11s, cc := layer-1 c1
    #pragma unroll
    for (int mt = 0; mt < 4; ++mt) {
        half4_t hv;
        #pragma unroll
        for (int r = 0; r < 4; ++r) {
            float c1 = sig2(acc[mt][0][r]) * tanh2(acc[mt][2][r]);
            cc[mt][r] = c1;
            hv[r] = (_Float16)(sig2(acc[mt][3][r]) * tanh2(c1 * L2E2));
        }
        *(half4_t*)(H11s + swz(mt * 16 + c, w * 32 + q * 8)) = hv;
    }
    __syncthreads();   // [S3-barrier] H2s + H11s ready

    // ---- S4: layer1 step2 --------------------------------------------------
    #pragma unroll
    for (int g = 0; g < 4; ++g)
        #pragma unroll
        for (int mt = 0; mt < 4; ++mt) acc[mt][g] = bv1[g];
    {
        const _Float16* Wa = Wp_in + WP_WIH1; asm volatile("" : "+s"(Wa));
        const _Float16* Wb = Wp_in + WP_WHH1; asm volatile("" : "+s"(Wb));
        __builtin_amdgcn_s_setprio(1);
        gemm_lds<4>(Wa, H2s,  w, lane, acc);
        gemm_lds<4>(Wb, H11s, w, lane, acc);
        __builtin_amdgcn_s_setprio(0);
    }
    // epilogue: h2_1 -> relu -> dot fc_w; partials straight to L2 atomics
    // (out pre-inited with fc_b in preamble; only this wg touches these 64
    //  rows; init/atomic ordering guaranteed by the barriers above).
    {
        const float* fc_w = fc_w_in; asm volatile("" : "+s"(fc_w));
        f32x4 fwv = ((const f32x4*)fc_w)[bq_idx];
        #pragma unroll
        for (int mt = 0; mt < 4; ++mt) {
            float v = 0.0f;
            #pragma unroll
            for (int r = 0; r < 4; ++r) {
                float c2 = sig2(acc[mt][1][r]) * cc[mt][r]
                         + sig2(acc[mt][0][r]) * tanh2(acc[mt][2][r]);
                float h  = sig2(acc[mt][3][r]) * tanh2(c2 * L2E2);
                v = fmaf(fmaxf(h, 0.0f), fwv[r], v);
            }
            v += __shfl_xor(v, 16);
            v += __shfl_xor(v, 32);
            if (lane < 16)
                atomicAdd(out + (size_t)wg * 64 + mt * 16 + lane, v);
        }
    }
}

extern "C" void kernel_launch(void* const* d_in, const int* in_sizes, int n_in,
                              void* d_out, int out_size, void* d_ws, size_t ws_size,
                              hipStream_t stream)
{
    const float* x    = (const float*)d_in[0];
    const float* mu   = (const float*)d_in[1];
    const float* Wih0 = (const float*)d_in[2];
    const float* Whh0 = (const float*)d_in[3];
    const float* bih0 = (const float*)d_in[4];
    const float* bhh0 = (const float*)d_in[5];
    const float* Wih1 = (const float*)d_in[6];
    const float* Whh1 = (const float*)d_in[7];
    const float* bih1 = (const float*)d_in[8];
    const float* bhh1 = (const float*)d_in[9];
    const float* fcw  = (const float*)d_in[10];
    const float* fcb  = (const float*)d_in[11];
    float* out = (float*)d_out;

    _Float16* Wp  = (_Float16*)d_ws;
    float* bias0f = (float*)((char*)d_ws + WS_BIAS0);
    float* bias1f = (float*)((char*)d_ws + WS_BIAS1);
    float* mu_g2  = (float*)((char*)d_ws + WS_MUG2);

    hipLaunchKernelGGL(prep_kernel, dim3(241), dim3(256), 0, stream,
                       Wih0, Whh0, Wih1, Whh1, bih0, bhh0, bih1, bhh1, mu,
                       Wp, bias0f, bias1f, mu_g2);
    hipLaunchKernelGGL(lstm_main, dim3(1024), dim3(512), 0, stream,
                       x, Wp, bias0f, bias1f, mu_g2, fcw, fcb, out);
}

// Round 4
// 134.725 us; speedup vs baseline: 1.2890x; 1.0744x over previous
//
#include <hip/hip_runtime.h>

// Forecaster: B=64, S=1024, F=64, H=128. N = B*S = 65536 independent instances.
// R14 (resubmit; R3 bench was a GPUAcquisitionTimeout — never measured).
// Weight-load software pipeline. R13 post-mortem:
//  - SQ_LDS_BANK_CONFLICT identical (2752512) across swizzled/non-swizzled
//    layouts -> counter is shfl/staging-structural, NOT the H tiles; both
//    layouts are conflict-free at the 16-lane-phase floor. Dead end closed.
//  - R13's real regression: S3 per-mt bq reload = +393MB L2 weight traffic.
//  - Real limiter: ~40% neither-pipe-busy = exposed L2 latency on the 16
//    dependent global weight loads per gemm stage (no pipelining).
// Changes vs R13 (math identical):
//  1. S3 back to shared-bq (weight traffic back to 576KB/wg).
//  2. All gemms double-buffer bq: load kc+1 during kc's MFMA; the LAST kc
//     loads the NEXT stage's kc=0 weights, so stage epilogues (300+ cyc of
//     VALU) cover cross-stage load latency.
//  3. lgkm-only barriers (s_waitcnt lgkmcnt(0) + raw s_barrier): prefetched
//     global loads ride across barriers instead of dying to the compiler's
//     vmcnt(0) drain (m97 stall).
//  4. Bias enters as MFMA C operand at kc=0: kills 64 v_mov/stage acc-init
//     and removes bias-load latency from the MFMA critical path.
// Kept: no min-waves clamp (R4/R12); A0 LDS staging (R12 spill lesson);
// 1-tile wgs grid 1024; swizzled H tiles (LDS-size win only); setprio.

typedef _Float16 half8 __attribute__((ext_vector_type(8)));
typedef _Float16 half4_t __attribute__((ext_vector_type(4)));
typedef float f32x4 __attribute__((ext_vector_type(4)));

#define L2E  1.4426950408889634f
#define L2E2 2.8853900817779268f

#define WP_WIH0 0
#define WP_WHH0 32768
#define WP_WIH1 98304
#define WP_WHH1 163840
#define WS_BIAS0 458752            // bytes
#define WS_BIAS1 (458752 + 2048)
#define WS_MUG2  (458752 + 4096)

// ---------------- merged prep kernel (unchanged) ----------------------------
__global__ void prep_kernel(const float* __restrict__ Wih0,
                            const float* __restrict__ Whh0,
                            const float* __restrict__ Wih1,
                            const float* __restrict__ Whh1,
                            const float* __restrict__ bih0,
                            const float* __restrict__ bhh0,
                            const float* __restrict__ bih1,
                            const float* __restrict__ bhh1,
                            const float* __restrict__ mu,
                            _Float16* __restrict__ Wp,
                            float* __restrict__ bias0f,
                            float* __restrict__ bias1f,
                            float* __restrict__ mu_g2)
{
    int blk = blockIdx.x;
    if (blk >= 113) {                       // ---- mu_g2 part
        int o = (blk - 113) * 256 + threadIdx.x;   // 0..32767
        int b = o >> 9;
        int n = o & 511;
        float s = bih0[n] + bhh0[n];
        const float* m = mu + b * 64;
        const float* wrow = Wih0 + n * 64;
        #pragma unroll 8
        for (int k = 0; k < 64; ++k) s += m[k] * wrow[k];
        float scale = ((n >> 7) == 2) ? L2E2 : L2E;
        mu_g2[o] = s * scale;
        return;
    }
    if (blk == 112) {                       // ---- bias part
        int i = threadIdx.x;
        float sc_hi = (i < 128) ? L2E2 : L2E;
        bias0f[i]       = (bih0[i]       + bhh0[i])       * L2E;
        bias0f[i + 256] = (bih0[i + 256] + bhh0[i + 256]) * sc_hi;
        bias1f[i]       = (bih1[i]       + bhh1[i])       * L2E;
        bias1f[i + 256] = (bih1[i + 256] + bhh1[i + 256]) * sc_hi;
        return;
    }
    // ---- weight pack: [nt][kc][lane][8], c=lane&15 -> n=nt*16+c,
    //      q=lane>>4 -> k = kc*32 + q*8 .. +8  (scaled by gate)
    int gidx = blk * 256 + threadIdx.x;     // 0..28671 groups of 8 halfs
    const float* src; int KC, Kw, local;
    if (gidx < 4096)       { src = Wih0; KC = 2; Kw = 64;  local = gidx; }
    else if (gidx < 12288) { src = Whh0; KC = 4; Kw = 128; local = gidx - 4096; }
    else if (gidx < 20480) { src = Wih1; KC = 4; Kw = 128; local = gidx - 12288; }
    else                   { src = Whh1; KC = 4; Kw = 128; local = gidx - 20480; }
    int lane = local & 63;
    int tmp  = local >> 6;
    int kc   = tmp % KC;
    int nt   = tmp / KC;
    int n  = nt * 16 + (lane & 15);
    int k0 = kc * 32 + (lane >> 4) * 8;
    float scale = ((n >> 7) == 2) ? L2E2 : L2E;
    const float* s = src + n * Kw + k0;
    half8 hv;
    #pragma unroll
    for (int j = 0; j < 8; ++j) hv[j] = (_Float16)(s[j] * scale);
    *(half8*)(Wp + (size_t)gidx * 8) = hv;
}

// ---------------- bare-metal gate math -------------------------------------
__device__ __forceinline__ float sig2(float a) {
    return __builtin_amdgcn_rcpf(1.0f + __builtin_amdgcn_exp2f(-a));
}
__device__ __forceinline__ float tanh2(float a) {
    return fmaf(-2.0f, __builtin_amdgcn_rcpf(1.0f + __builtin_amdgcn_exp2f(a)), 1.0f);
}

// Swizzled byte offset into a [64 rows][256B] H tile (involution; same on
// write and read). Kept for the LDS-size win (stride-128 tiles).
__device__ __forceinline__ int swz(int row, int col) {
    return (row << 8) + (col ^ ((row & 7) << 4));
}

// lgkm-only barrier: orders LDS writes across the wg WITHOUT draining vmcnt,
// so prefetched global weight loads stay in flight across it (T3/T4).
__device__ __forceinline__ void lds_barrier() {
    asm volatile("s_waitcnt lgkmcnt(0)" ::: "memory");
    __builtin_amdgcn_s_barrier();
    asm volatile("" ::: "memory");
}

__device__ __forceinline__ void load_bq(half8 bq[4], const _Float16* __restrict__ Wq,
                                        int KC, int kc, int w, int lane)
{
    #pragma unroll
    for (int g = 0; g < 4; ++g)
        bq[g] = *(const half8*)(Wq + (((g * 8 + w) * KC + kc) * 64 + lane) * 8);
}

template<int SRC>   // 0 = A0 (stride 72 halfs), 1 = swizzled H tile
__device__ __forceinline__ void load_a(half8 a[4], const char* base, int kc, int c, int q)
{
    #pragma unroll
    for (int mt = 0; mt < 4; ++mt) {
        if (SRC == 0)
            a[mt] = *(const half8*)((const _Float16*)base + (mt * 16 + c) * 72 + kc * 32 + q * 8);
        else
            a[mt] = *(const half8*)(base + swz(mt * 16 + c, kc * 64 + q * 16));
    }
}

// One gemm stage with bq double-buffering. On entry bqc holds THIS stage's
// kc=0 weights (prefetched by the previous stage / preamble). On exit bqc
// holds the NEXT stage's kc=0 weights (if PF). FIRST: use bv[g] as the MFMA
// C operand at kc=0 (bias init without v_movs); else accumulate into acc.
template<int KC, int SRC, bool PF, bool FIRST>
__device__ __forceinline__ void gemm_pf(const _Float16* __restrict__ Wq,
                                        const char* Abase,
                                        const _Float16* __restrict__ Wnext, int KCnext,
                                        half8 bqc[4], const f32x4 bv[4],
                                        int w, int lane, f32x4 acc[4][4])
{
    const int c = lane & 15, q = lane >> 4;
    #pragma unroll
    for (int kc = 0; kc < KC; ++kc) {
        half8 bqn[4];
        if (kc + 1 < KC)  load_bq(bqn, Wq, KC, kc + 1, w, lane);
        else if (PF)      load_bq(bqn, Wnext, KCnext, 0, w, lane);
        half8 a[4];
        load_a<SRC>(a, Abase, kc, c, q);
        __builtin_amdgcn_s_setprio(1);
        #pragma unroll
        for (int mt = 0; mt < 4; ++mt)
            #pragma unroll
            for (int g = 0; g < 4; ++g) {
                f32x4 cin = (FIRST && kc == 0) ? bv[g] : acc[mt][g];
                acc[mt][g] = __builtin_amdgcn_mfma_f32_16x16x32_f16(bqc[g], a[mt], cin, 0, 0, 0);
            }
        __builtin_amdgcn_s_setprio(0);
        if (kc + 1 < KC || PF) {
            #pragma unroll
            for (int g = 0; g < 4; ++g) bqc[g] = bqn[g];
        }
    }
}

__global__ __launch_bounds__(512) void lstm_main(
    const float* __restrict__ x, const _Float16* __restrict__ Wp_in,
    const float* __restrict__ bias0f_in, const float* __restrict__ bias1f_in,
    const float* __restrict__ mu_g2_in, const float* __restrict__ fc_w_in,
    const float* __restrict__ fc_b_in, float* __restrict__ out)
{
    // LDS 58368 B (2 wg/CU = 116.7 KB <= 160):
    //  [0, 16384)       H1s   (swizzled [64][256B])
    //  [16384, 32768)   H2s
    //  [32768, 49152)   H11s
    //  [49152, 58368)   A0    (64 x 72 halfs, coalesced staging)
    __shared__ __align__(16) char smem[58368];
    char* H1s  = smem;
    char* H2s  = smem + 16384;
    char* H11s = smem + 32768;
    _Float16* A0 = (_Float16*)(smem + 49152);

    const int t = threadIdx.x;
    const int w = t >> 6, lane = t & 63, c = lane & 15, q = lane >> 4;
    const int wg = blockIdx.x;                   // 1024 wgs x 64 rows
    const int b = wg >> 4;                       // 16 wgs (1024 rows) per batch
    const int bq_idx = w * 4 + q;                // float4 index of (w,q) slice

    // ---- prefetch S1 kc=0 weights with maximum lead -----------------------
    half8 bqc[4];
    load_bq(bqc, Wp_in + WP_WIH0, 2, 0, w, lane);

    // ---- preamble: stage x tile into A0 (coalesced); init out rows --------
    {
        const float* xp = x + (size_t)wg * 4096 + t * 8;
        float4 u0 = ((const float4*)xp)[0];
        float4 u1 = ((const float4*)xp)[1];
        half8 hv;
        hv[0] = (_Float16)u0.x; hv[1] = (_Float16)u0.y;
        hv[2] = (_Float16)u0.z; hv[3] = (_Float16)u0.w;
        hv[4] = (_Float16)u1.x; hv[5] = (_Float16)u1.y;
        hv[6] = (_Float16)u1.z; hv[7] = (_Float16)u1.w;
        *(half8*)(A0 + (t >> 3) * 72 + (t & 7) * 8) = hv;
        if (t < 64) out[(size_t)wg * 64 + t] = fc_b_in[0];
    }
    lds_barrier();   // A0 visible (lgkm); out-init retires long before S4 atomics

    f32x4 acc[4][4];
    float cc[4][4];

    // ---- S1: layer0 step1 (A from A0; bias0 as MFMA C) --------------------
    {
        f32x4 bv[4];
        {
            const float* bias0f = bias0f_in; asm volatile("" : "+s"(bias0f));
            #pragma unroll
            for (int g = 0; g < 4; ++g)
                bv[g] = ((const f32x4*)bias0f)[g * 32 + bq_idx];
        }
        gemm_pf<2, 0, true, true>(Wp_in + WP_WIH0, (const char*)A0,
                                  Wp_in + WP_WHH0, 4, bqc, bv, w, lane, acc);
    }
    #pragma unroll
    for (int mt = 0; mt < 4; ++mt) {
        half4_t hv;
        #pragma unroll
        for (int r = 0; r < 4; ++r) {
            float c1 = sig2(acc[mt][0][r]) * tanh2(acc[mt][2][r]);
            cc[mt][r] = c1;
            hv[r] = (_Float16)(sig2(acc[mt][3][r]) * tanh2(c1 * L2E2));
        }
        *(half4_t*)(H1s + swz(mt * 16 + c, w * 32 + q * 8)) = hv;
    }
    lds_barrier();   // [S1-barrier] H1s ready; Whh0 kc=0 still in flight

    // ---- S2: layer0 step2 (A from H1s; mu_g2 as MFMA C) -------------------
    {
        f32x4 bv[4];
        {
            const float* mu_g2b = mu_g2_in + b * 512; asm volatile("" : "+s"(mu_g2b));
            #pragma unroll
            for (int g = 0; g < 4; ++g)
                bv[g] = ((const f32x4*)mu_g2b)[g * 32 + bq_idx];
        }
        gemm_pf<4, 1, true, true>(Wp_in + WP_WHH0, H1s,
                                  Wp_in + WP_WIH1, 4, bqc, bv, w, lane, acc);
    }
    // epi2: h2 -> H2s (no barrier: S3 reads only H1s, stable since S1-barrier)
    #pragma unroll
    for (int mt = 0; mt < 4; ++mt) {
        half4_t hv;
        #pragma unroll
        for (int r = 0; r < 4; ++r) {
            float c2 = sig2(acc[mt][1][r]) * cc[mt][r]
                     + sig2(acc[mt][0][r]) * tanh2(acc[mt][2][r]);
            hv[r] = (_Float16)(sig2(acc[mt][3][r]) * tanh2(c2 * L2E2));
        }
        *(half4_t*)(H2s + swz(mt * 16 + c, w * 32 + q * 8)) = hv;
    }

    // ---- S3: layer1 step1 (A from H1s; bias1 as MFMA C) -------------------
    // Tail-prefetches Wih1 kc=0 AGAIN (S4a uses the same matrix; L2-hot).
    {
        f32x4 bv[4];
        {
            const float* bias1f = bias1f_in; asm volatile("" : "+s"(bias1f));
            #pragma unroll
            for (int g = 0; g < 4; ++g)
                bv[g] = ((const f32x4*)bias1f)[g * 32 + bq_idx];
        }
        gemm_pf<4, 1, true, true>(Wp_in + WP_WIH1, H1s,
                                  Wp_in + WP_WIH1, 4, bqc, bv, w, lane, acc);
    }
    // epi3: h11 -> H11s, cc := layer-1 c1
    #pragma unroll
    for (int mt = 0; mt < 4; ++mt) {
        half4_t hv;
        #pragma unroll
        for (int r = 0; r < 4; ++r) {
            float c1 = sig2(acc[mt][0][r]) * tanh2(acc[mt][2][r]);
            cc[mt][r] = c1;
            hv[r] = (_Float16)(sig2(acc[mt][3][r]) * tanh2(c1 * L2E2));
        }
        *(half4_t*)(H11s + swz(mt * 16 + c, w * 32 + q * 8)) = hv;
    }
    lds_barrier();   // [S3-barrier] H2s + H11s ready; Wih1 kc=0 in flight

    // ---- S4: layer1 step2 (Wih1@H2s + Whh1@H11s; bias1 as MFMA C) ---------
    {
        f32x4 bv[4];
        {
            const float* bias1f = bias1f_in; asm volatile("" : "+s"(bias1f));
            #pragma unroll
            for (int g = 0; g < 4; ++g)
                bv[g] = ((const f32x4*)bias1f)[g * 32 + bq_idx];
        }
        gemm_pf<4, 1, true, true>(Wp_in + WP_WIH1, H2s,
                                  Wp_in + WP_WHH1, 4, bqc, bv, w, lane, acc);
    }
    gemm_pf<4, 1, false, false>(Wp_in + WP_WHH1, H11s,
                                nullptr, 0, bqc, nullptr, w, lane, acc);

    // epilogue: h2_1 -> relu -> dot fc_w; partials straight to L2 atomics
    // (out pre-inited with fc_b in preamble; only this wg touches these 64
    //  rows; the store retires during the intervening vmcnt traffic).
    {
        const float* fc_w = fc_w_in; asm volatile("" : "+s"(fc_w));
        f32x4 fwv = ((const f32x4*)fc_w)[bq_idx];
        #pragma unroll
        for (int mt = 0; mt < 4; ++mt) {
            float v = 0.0f;
            #pragma unroll
            for (int r = 0; r < 4; ++r) {
                float c2 = sig2(acc[mt][1][r]) * cc[mt][r]
                         + sig2(acc[mt][0][r]) * tanh2(acc[mt][2][r]);
                float h  = sig2(acc[mt][3][r]) * tanh2(c2 * L2E2);
                v = fmaf(fmaxf(h, 0.0f), fwv[r], v);
            }
            v += __shfl_xor(v, 16);
            v += __shfl_xor(v, 32);
            if (lane < 16)
                atomicAdd(out + (size_t)wg * 64 + mt * 16 + lane, v);
        }
    }
}

extern "C" void kernel_launch(void* const* d_in, const int* in_sizes, int n_in,
                              void* d_out, int out_size, void* d_ws, size_t ws_size,
                              hipStream_t stream)
{
    const float* x    = (const float*)d_in[0];
    const float* mu   = (const float*)d_in[1];
    const float* Wih0 = (const float*)d_in[2];
    const float* Whh0 = (const float*)d_in[3];
    const float* bih0 = (const float*)d_in[4];
    const float* bhh0 = (const float*)d_in[5];
    const float* Wih1 = (const float*)d_in[6];
    const float* Whh1 = (const float*)d_in[7];
    const float* bih1 = (const float*)d_in[8];
    const float* bhh1 = (const float*)d_in[9];
    const float* fcw  = (const float*)d_in[10];
    const float* fcb  = (const float*)d_in[11];
    float* out = (float*)d_out;

    _Float16* Wp  = (_Float16*)d_ws;
    float* bias0f = (float*)((char*)d_ws + WS_BIAS0);
    float* bias1f = (float*)((char*)d_ws + WS_BIAS1);
    float* mu_g2  = (float*)((char*)d_ws + WS_MUG2);

    hipLaunchKernelGGL(prep_kernel, dim3(241), dim3(256), 0, stream,
                       Wih0, Whh0, Wih1, Whh1, bih0, bhh0, bih1, bhh1, mu,
                       Wp, bias0f, bias1f, mu_g2);
    hipLaunchKernelGGL(lstm_main, dim3(1024), dim3(512), 0, stream,
                       x, Wp, bias0f, bias1f, mu_g2, fcw, fcb, out);
}

// Round 5
// 133.628 us; speedup vs baseline: 1.2995x; 1.0082x over previous
//
#include <hip/hip_runtime.h>

// Forecaster: B=64, S=1024, F=64, H=128. N = B*S = 65536 independent instances.
// R15: occupancy attack — A0 aliased into H2s region. R14 post-mortem:
// pipeline worked (73->61us, MfmaUtil 23, VALUBusy 47.5, VGPR 80, no spill).
// Remaining ~29% neither-busy with only 2 wg/CU (4 waves/SIMD) resident.
// Single change vs R14 (math + schedule identical):
//  - A0 staging buffer aliases the H2s region. A0 is dead after the S1 gemm
//    (all waves' ds_reads drained by the lgkmcnt(0) inside the S1-barrier);
//    H2s is first written in epi2, strictly after the S1-barrier. LDS
//    58368 -> 49152 B => 3 wg/CU (147.4KB <= 160). VGPR=80 supports 6
//    waves/SIMD (480 <= 512), so occupancy 16 -> 24 waves/CU (+50%).
//  - DELIBERATELY no other edits: any +VGPR past 85 would cap at 5
//    waves/SIMD -> wg granularity rounds back down to 2 wg/CU (this is why
//    the a-operand double-buffer was rejected this round).
// Kept from R14: bq double-buffer pipeline across stages; lgkm-only
// barriers (prefetches ride across); bias as MFMA C at kc=0; no min-waves
// clamp (R4/R12); A0 LDS staging (R12); 1-tile wgs grid 1024; swizzled H
// tiles; setprio around MFMA clusters.

typedef _Float16 half8 __attribute__((ext_vector_type(8)));
typedef _Float16 half4_t __attribute__((ext_vector_type(4)));
typedef float f32x4 __attribute__((ext_vector_type(4)));

#define L2E  1.4426950408889634f
#define L2E2 2.8853900817779268f

#define WP_WIH0 0
#define WP_WHH0 32768
#define WP_WIH1 98304
#define WP_WHH1 163840
#define WS_BIAS0 458752            // bytes
#define WS_BIAS1 (458752 + 2048)
#define WS_MUG2  (458752 + 4096)

// ---------------- merged prep kernel (unchanged) ----------------------------
__global__ void prep_kernel(const float* __restrict__ Wih0,
                            const float* __restrict__ Whh0,
                            const float* __restrict__ Wih1,
                            const float* __restrict__ Whh1,
                            const float* __restrict__ bih0,
                            const float* __restrict__ bhh0,
                            const float* __restrict__ bih1,
                            const float* __restrict__ bhh1,
                            const float* __restrict__ mu,
                            _Float16* __restrict__ Wp,
                            float* __restrict__ bias0f,
                            float* __restrict__ bias1f,
                            float* __restrict__ mu_g2)
{
    int blk = blockIdx.x;
    if (blk >= 113) {                       // ---- mu_g2 part
        int o = (blk - 113) * 256 + threadIdx.x;   // 0..32767
        int b = o >> 9;
        int n = o & 511;
        float s = bih0[n] + bhh0[n];
        const float* m = mu + b * 64;
        const float* wrow = Wih0 + n * 64;
        #pragma unroll 8
        for (int k = 0; k < 64; ++k) s += m[k] * wrow[k];
        float scale = ((n >> 7) == 2) ? L2E2 : L2E;
        mu_g2[o] = s * scale;
        return;
    }
    if (blk == 112) {                       // ---- bias part
        int i = threadIdx.x;
        float sc_hi = (i < 128) ? L2E2 : L2E;
        bias0f[i]       = (bih0[i]       + bhh0[i])       * L2E;
        bias0f[i + 256] = (bih0[i + 256] + bhh0[i + 256]) * sc_hi;
        bias1f[i]       = (bih1[i]       + bhh1[i])       * L2E;
        bias1f[i + 256] = (bih1[i + 256] + bhh1[i + 256]) * sc_hi;
        return;
    }
    // ---- weight pack: [nt][kc][lane][8], c=lane&15 -> n=nt*16+c,
    //      q=lane>>4 -> k = kc*32 + q*8 .. +8  (scaled by gate)
    int gidx = blk * 256 + threadIdx.x;     // 0..28671 groups of 8 halfs
    const float* src; int KC, Kw, local;
    if (gidx < 4096)       { src = Wih0; KC = 2; Kw = 64;  local = gidx; }
    else if (gidx < 12288) { src = Whh0; KC = 4; Kw = 128; local = gidx - 4096; }
    else if (gidx < 20480) { src = Wih1; KC = 4; Kw = 128; local = gidx - 12288; }
    else                   { src = Whh1; KC = 4; Kw = 128; local = gidx - 20480; }
    int lane = local & 63;
    int tmp  = local >> 6;
    int kc   = tmp % KC;
    int nt   = tmp / KC;
    int n  = nt * 16 + (lane & 15);
    int k0 = kc * 32 + (lane >> 4) * 8;
    float scale = ((n >> 7) == 2) ? L2E2 : L2E;
    const float* s = src + n * Kw + k0;
    half8 hv;
    #pragma unroll
    for (int j = 0; j < 8; ++j) hv[j] = (_Float16)(s[j] * scale);
    *(half8*)(Wp + (size_t)gidx * 8) = hv;
}

// ---------------- bare-metal gate math -------------------------------------
__device__ __forceinline__ float sig2(float a) {
    return __builtin_amdgcn_rcpf(1.0f + __builtin_amdgcn_exp2f(-a));
}
__device__ __forceinline__ float tanh2(float a) {
    return fmaf(-2.0f, __builtin_amdgcn_rcpf(1.0f + __builtin_amdgcn_exp2f(a)), 1.0f);
}

// Swizzled byte offset into a [64 rows][256B] H tile (involution; same on
// write and read). Kept for the LDS-size win (stride-128 tiles).
__device__ __forceinline__ int swz(int row, int col) {
    return (row << 8) + (col ^ ((row & 7) << 4));
}

// lgkm-only barrier: orders LDS writes across the wg WITHOUT draining vmcnt,
// so prefetched global weight loads stay in flight across it (T3/T4).
__device__ __forceinline__ void lds_barrier() {
    asm volatile("s_waitcnt lgkmcnt(0)" ::: "memory");
    __builtin_amdgcn_s_barrier();
    asm volatile("" ::: "memory");
}

__device__ __forceinline__ void load_bq(half8 bq[4], const _Float16* __restrict__ Wq,
                                        int KC, int kc, int w, int lane)
{
    #pragma unroll
    for (int g = 0; g < 4; ++g)
        bq[g] = *(const half8*)(Wq + (((g * 8 + w) * KC + kc) * 64 + lane) * 8);
}

template<int SRC>   // 0 = A0 (stride 72 halfs), 1 = swizzled H tile
__device__ __forceinline__ void load_a(half8 a[4], const char* base, int kc, int c, int q)
{
    #pragma unroll
    for (int mt = 0; mt < 4; ++mt) {
        if (SRC == 0)
            a[mt] = *(const half8*)((const _Float16*)base + (mt * 16 + c) * 72 + kc * 32 + q * 8);
        else
            a[mt] = *(const half8*)(base + swz(mt * 16 + c, kc * 64 + q * 16));
    }
}

// One gemm stage with bq double-buffering. On entry bqc holds THIS stage's
// kc=0 weights (prefetched by the previous stage / preamble). On exit bqc
// holds the NEXT stage's kc=0 weights (if PF). FIRST: use bv[g] as the MFMA
// C operand at kc=0 (bias init without v_movs); else accumulate into acc.
template<int KC, int SRC, bool PF, bool FIRST>
__device__ __forceinline__ void gemm_pf(const _Float16* __restrict__ Wq,
                                        const char* Abase,
                                        const _Float16* __restrict__ Wnext, int KCnext,
                                        half8 bqc[4], const f32x4 bv[4],
                                        int w, int lane, f32x4 acc[4][4])
{
    const int c = lane & 15, q = lane >> 4;
    #pragma unroll
    for (int kc = 0; kc < KC; ++kc) {
        half8 bqn[4];
        if (kc + 1 < KC)  load_bq(bqn, Wq, KC, kc + 1, w, lane);
        else if (PF)      load_bq(bqn, Wnext, KCnext, 0, w, lane);
        half8 a[4];
        load_a<SRC>(a, Abase, kc, c, q);
        __builtin_amdgcn_s_setprio(1);
        #pragma unroll
        for (int mt = 0; mt < 4; ++mt)
            #pragma unroll
            for (int g = 0; g < 4; ++g) {
                f32x4 cin = (FIRST && kc == 0) ? bv[g] : acc[mt][g];
                acc[mt][g] = __builtin_amdgcn_mfma_f32_16x16x32_f16(bqc[g], a[mt], cin, 0, 0, 0);
            }
        __builtin_amdgcn_s_setprio(0);
        if (kc + 1 < KC || PF) {
            #pragma unroll
            for (int g = 0; g < 4; ++g) bqc[g] = bqn[g];
        }
    }
}

__global__ __launch_bounds__(512) void lstm_main(
    const float* __restrict__ x, const _Float16* __restrict__ Wp_in,
    const float* __restrict__ bias0f_in, const float* __restrict__ bias1f_in,
    const float* __restrict__ mu_g2_in, const float* __restrict__ fc_w_in,
    const float* __restrict__ fc_b_in, float* __restrict__ out)
{
    // LDS 49152 B (3 wg/CU = 147.4 KB <= 160):
    //  [0, 16384)       H1s   (swizzled [64][256B])
    //  [16384, 32768)   H2s   -- ALSO hosts A0 (64 x 72 halfs = 9216 B):
    //                      A0 lives [preamble, S1-gemm]; dead at S1-barrier
    //                      (ds_reads drained by lgkmcnt(0)); H2s first
    //                      written in epi2, strictly after S1-barrier.
    //  [32768, 49152)   H11s
    __shared__ __align__(16) char smem[49152];
    char* H1s  = smem;
    char* H2s  = smem + 16384;
    char* H11s = smem + 32768;
    _Float16* A0 = (_Float16*)(smem + 16384);    // alias of H2s region

    const int t = threadIdx.x;
    const int w = t >> 6, lane = t & 63, c = lane & 15, q = lane >> 4;
    const int wg = blockIdx.x;                   // 1024 wgs x 64 rows
    const int b = wg >> 4;                       // 16 wgs (1024 rows) per batch
    const int bq_idx = w * 4 + q;                // float4 index of (w,q) slice

    // ---- prefetch S1 kc=0 weights with maximum lead -----------------------
    half8 bqc[4];
    load_bq(bqc, Wp_in + WP_WIH0, 2, 0, w, lane);

    // ---- preamble: stage x tile into A0 (coalesced); init out rows --------
    {
        const float* xp = x + (size_t)wg * 4096 + t * 8;
        float4 u0 = ((const float4*)xp)[0];
        float4 u1 = ((const float4*)xp)[1];
        half8 hv;
        hv[0] = (_Float16)u0.x; hv[1] = (_Float16)u0.y;
        hv[2] = (_Float16)u0.z; hv[3] = (_Float16)u0.w;
        hv[4] = (_Float16)u1.x; hv[5] = (_Float16)u1.y;
        hv[6] = (_Float16)u1.z; hv[7] = (_Float16)u1.w;
        *(half8*)(A0 + (t >> 3) * 72 + (t & 7) * 8) = hv;
        if (t < 64) out[(size_t)wg * 64 + t] = fc_b_in[0];
    }
    lds_barrier();   // A0 visible (lgkm); out-init retires long before S4 atomics

    f32x4 acc[4][4];
    float cc[4][4];

    // ---- S1: layer0 step1 (A from A0; bias0 as MFMA C) --------------------
    {
        f32x4 bv[4];
        {
            const float* bias0f = bias0f_in; asm volatile("" : "+s"(bias0f));
            #pragma unroll
            for (int g = 0; g < 4; ++g)
                bv[g] = ((const f32x4*)bias0f)[g * 32 + bq_idx];
        }
        gemm_pf<2, 0, true, true>(Wp_in + WP_WIH0, (const char*)A0,
                                  Wp_in + WP_WHH0, 4, bqc, bv, w, lane, acc);
    }
    #pragma unroll
    for (int mt = 0; mt < 4; ++mt) {
        half4_t hv;
        #pragma unroll
        for (int r = 0; r < 4; ++r) {
            float c1 = sig2(acc[mt][0][r]) * tanh2(acc[mt][2][r]);
            cc[mt][r] = c1;
            hv[r] = (_Float16)(sig2(acc[mt][3][r]) * tanh2(c1 * L2E2));
        }
        *(half4_t*)(H1s + swz(mt * 16 + c, w * 32 + q * 8)) = hv;
    }
    lds_barrier();   // [S1-barrier] H1s ready; A0 now dead; Whh0 kc=0 in flight

    // ---- S2: layer0 step2 (A from H1s; mu_g2 as MFMA C) -------------------
    {
        f32x4 bv[4];
        {
            const float* mu_g2b = mu_g2_in + b * 512; asm volatile("" : "+s"(mu_g2b));
            #pragma unroll
            for (int g = 0; g < 4; ++g)
                bv[g] = ((const f32x4*)mu_g2b)[g * 32 + bq_idx];
        }
        gemm_pf<4, 1, true, true>(Wp_in + WP_WHH0, H1s,
                                  Wp_in + WP_WIH1, 4, bqc, bv, w, lane, acc);
    }
    // epi2: h2 -> H2s (overwrites dead A0; no barrier: S3 reads only H1s)
    #pragma unroll
    for (int mt = 0; mt < 4; ++mt) {
        half4_t hv;
        #pragma unroll
        for (int r = 0; r < 4; ++r) {
            float c2 = sig2(acc[mt][1][r]) * cc[mt][r]
                     + sig2(acc[mt][0][r]) * tanh2(acc[mt][2][r]);
            hv[r] = (_Float16)(sig2(acc[mt][3][r]) * tanh2(c2 * L2E2));
        }
        *(half4_t*)(H2s + swz(mt * 16 + c, w * 32 + q * 8)) = hv;
    }

    // ---- S3: layer1 step1 (A from H1s; bias1 as MFMA C) -------------------
    // Tail-prefetches Wih1 kc=0 AGAIN (S4a uses the same matrix; L2-hot).
    {
        f32x4 bv[4];
        {
            const float* bias1f = bias1f_in; asm volatile("" : "+s"(bias1f));
            #pragma unroll
            for (int g = 0; g < 4; ++g)
                bv[g] = ((const f32x4*)bias1f)[g * 32 + bq_idx];
        }
        gemm_pf<4, 1, true, true>(Wp_in + WP_WIH1, H1s,
                                  Wp_in + WP_WIH1, 4, bqc, bv, w, lane, acc);
    }
    // epi3: h11 -> H11s, cc := layer-1 c1
    #pragma unroll
    for (int mt = 0; mt < 4; ++mt) {
        half4_t hv;
        #pragma unroll
        for (int r = 0; r < 4; ++r) {
            float c1 = sig2(acc[mt][0][r]) * tanh2(acc[mt][2][r]);
            cc[mt][r] = c1;
            hv[r] = (_Float16)(sig2(acc[mt][3][r]) * tanh2(c1 * L2E2));
        }
        *(half4_t*)(H11s + swz(mt * 16 + c, w * 32 + q * 8)) = hv;
    }
    lds_barrier();   // [S3-barrier] H2s + H11s ready; Wih1 kc=0 in flight

    // ---- S4: layer1 step2 (Wih1@H2s + Whh1@H11s; bias1 as MFMA C) ---------
    {
        f32x4 bv[4];
        {
            const float* bias1f = bias1f_in; asm volatile("" : "+s"(bias1f));
            #pragma unroll
            for (int g = 0; g < 4; ++g)
                bv[g] = ((const f32x4*)bias1f)[g * 32 + bq_idx];
        }
        gemm_pf<4, 1, true, true>(Wp_in + WP_WIH1, H2s,
                                  Wp_in + WP_WHH1, 4, bqc, bv, w, lane, acc);
    }
    gemm_pf<4, 1, false, false>(Wp_in + WP_WHH1, H11s,
                                nullptr, 0, bqc, nullptr, w, lane, acc);

    // epilogue: h2_1 -> relu -> dot fc_w; partials straight to L2 atomics
    // (out pre-inited with fc_b in preamble; only this wg touches these 64
    //  rows; the store retires during the intervening vmcnt traffic).
    {
        const float* fc_w = fc_w_in; asm volatile("" : "+s"(fc_w));
        f32x4 fwv = ((const f32x4*)fc_w)[bq_idx];
        #pragma unroll
        for (int mt = 0; mt < 4; ++mt) {
            float v = 0.0f;
            #pragma unroll
            for (int r = 0; r < 4; ++r) {
                float c2 = sig2(acc[mt][1][r]) * cc[mt][r]
                         + sig2(acc[mt][0][r]) * tanh2(acc[mt][2][r]);
                float h  = sig2(acc[mt][3][r]) * tanh2(c2 * L2E2);
                v = fmaf(fmaxf(h, 0.0f), fwv[r], v);
            }
            v += __shfl_xor(v, 16);
            v += __shfl_xor(v, 32);
            if (lane < 16)
                atomicAdd(out + (size_t)wg * 64 + mt * 16 + lane, v);
        }
    }
}

extern "C" void kernel_launch(void* const* d_in, const int* in_sizes, int n_in,
                              void* d_out, int out_size, void* d_ws, size_t ws_size,
                              hipStream_t stream)
{
    const float* x    = (const float*)d_in[0];
    const float* mu   = (const float*)d_in[1];
    const float* Wih0 = (const float*)d_in[2];
    const float* Whh0 = (const float*)d_in[3];
    const float* bih0 = (const float*)d_in[4];
    const float* bhh0 = (const float*)d_in[5];
    const float* Wih1 = (const float*)d_in[6];
    const float* Whh1 = (const float*)d_in[7];
    const float* bih1 = (const float*)d_in[8];
    const float* bhh1 = (const float*)d_in[9];
    const float* fcw  = (const float*)d_in[10];
    const float* fcb  = (const float*)d_in[11];
    float* out = (float*)d_out;

    _Float16* Wp  = (_Float16*)d_ws;
    float* bias0f = (float*)((char*)d_ws + WS_BIAS0);
    float* bias1f = (float*)((char*)d_ws + WS_BIAS1);
    float* mu_g2  = (float*)((char*)d_ws + WS_MUG2);

    hipLaunchKernelGGL(prep_kernel, dim3(241), dim3(256), 0, stream,
                       Wih0, Whh0, Wih1, Whh1, bih0, bhh0, bih1, bhh1, mu,
                       Wp, bias0f, bias1f, mu_g2);
    hipLaunchKernelGGL(lstm_main, dim3(1024), dim3(512), 0, stream,
                       x, Wp, bias0f, bias1f, mu_g2, fcw, fcb, out);
}

// Round 6
// 133.543 us; speedup vs baseline: 1.3004x; 1.0006x over previous
//
#include <hip/hip_runtime.h>

// Forecaster: B=64, S=1024, F=64, H=128. N = B*S = 65536 independent instances.
// R16: 2-deep weight prefetch. R15 post-mortem: LDS 58368->49152 shipped but
// dur/Occupancy/MfmaUtil unchanged -> occupancy is NOT the lever (VGPR
// allocation quantum 128 keeps 2 wg/CU at VGPR=80; and/or extra wg gives 0).
// Corollary: VGPR 80..~128 is FREE (same bucket). Remaining ~30-35%
// neither-busy = per-kc exposed L2 latency: 1-deep bq prefetch leads by
// ~80-100 cyc vs ~200-300 cyc L2-hit latency (m125/m126).
// Single change vs R15 (math + barriers + LDS identical):
//  - bq ring [2][4]: at kc, issue loads for kc+2; stage tails prefetch the
//    NEXT stage's kc0+kc1, so epilogue VALU covers cross-stage lead.
//    Preamble preloads Wih0 kc0+kc1 with maximum lead.
//  - Abort criteria next round: VGPR>128 or WRITE_SIZE>3MB (spill).
// Kept: A0 aliases H2s (LDS 49152); lgkm-only barriers; bias as MFMA C;
// no min-waves clamp; 1-tile wgs grid 1024; swizzled H tiles; setprio.

typedef _Float16 half8 __attribute__((ext_vector_type(8)));
typedef _Float16 half4_t __attribute__((ext_vector_type(4)));
typedef float f32x4 __attribute__((ext_vector_type(4)));

#define L2E  1.4426950408889634f
#define L2E2 2.8853900817779268f

#define WP_WIH0 0
#define WP_WHH0 32768
#define WP_WIH1 98304
#define WP_WHH1 163840
#define WS_BIAS0 458752            // bytes
#define WS_BIAS1 (458752 + 2048)
#define WS_MUG2  (458752 + 4096)

// ---------------- merged prep kernel (unchanged) ----------------------------
__global__ void prep_kernel(const float* __restrict__ Wih0,
                            const float* __restrict__ Whh0,
                            const float* __restrict__ Wih1,
                            const float* __restrict__ Whh1,
                            const float* __restrict__ bih0,
                            const float* __restrict__ bhh0,
                            const float* __restrict__ bih1,
                            const float* __restrict__ bhh1,
                            const float* __restrict__ mu,
                            _Float16* __restrict__ Wp,
                            float* __restrict__ bias0f,
                            float* __restrict__ bias1f,
                            float* __restrict__ mu_g2)
{
    int blk = blockIdx.x;
    if (blk >= 113) {                       // ---- mu_g2 part
        int o = (blk - 113) * 256 + threadIdx.x;   // 0..32767
        int b = o >> 9;
        int n = o & 511;
        float s = bih0[n] + bhh0[n];
        const float* m = mu + b * 64;
        const float* wrow = Wih0 + n * 64;
        #pragma unroll 8
        for (int k = 0; k < 64; ++k) s += m[k] * wrow[k];
        float scale = ((n >> 7) == 2) ? L2E2 : L2E;
        mu_g2[o] = s * scale;
        return;
    }
    if (blk == 112) {                       // ---- bias part
        int i = threadIdx.x;
        float sc_hi = (i < 128) ? L2E2 : L2E;
        bias0f[i]       = (bih0[i]       + bhh0[i])       * L2E;
        bias0f[i + 256] = (bih0[i + 256] + bhh0[i + 256]) * sc_hi;
        bias1f[i]       = (bih1[i]       + bhh1[i])       * L2E;
        bias1f[i + 256] = (bih1[i + 256] + bhh1[i + 256]) * sc_hi;
        return;
    }
    // ---- weight pack: [nt][kc][lane][8], c=lane&15 -> n=nt*16+c,
    //      q=lane>>4 -> k = kc*32 + q*8 .. +8  (scaled by gate)
    int gidx = blk * 256 + threadIdx.x;     // 0..28671 groups of 8 halfs
    const float* src; int KC, Kw, local;
    if (gidx < 4096)       { src = Wih0; KC = 2; Kw = 64;  local = gidx; }
    else if (gidx < 12288) { src = Whh0; KC = 4; Kw = 128; local = gidx - 4096; }
    else if (gidx < 20480) { src = Wih1; KC = 4; Kw = 128; local = gidx - 12288; }
    else                   { src = Whh1; KC = 4; Kw = 128; local = gidx - 20480; }
    int lane = local & 63;
    int tmp  = local >> 6;
    int kc   = tmp % KC;
    int nt   = tmp / KC;
    int n  = nt * 16 + (lane & 15);
    int k0 = kc * 32 + (lane >> 4) * 8;
    float scale = ((n >> 7) == 2) ? L2E2 : L2E;
    const float* s = src + n * Kw + k0;
    half8 hv;
    #pragma unroll
    for (int j = 0; j < 8; ++j) hv[j] = (_Float16)(s[j] * scale);
    *(half8*)(Wp + (size_t)gidx * 8) = hv;
}

// ---------------- bare-metal gate math -------------------------------------
__device__ __forceinline__ float sig2(float a) {
    return __builtin_amdgcn_rcpf(1.0f + __builtin_amdgcn_exp2f(-a));
}
__device__ __forceinline__ float tanh2(float a) {
    return fmaf(-2.0f, __builtin_amdgcn_rcpf(1.0f + __builtin_amdgcn_exp2f(a)), 1.0f);
}

// Swizzled byte offset into a [64 rows][256B] H tile (involution; same on
// write and read). Kept for the LDS-size win (stride-128 tiles).
__device__ __forceinline__ int swz(int row, int col) {
    return (row << 8) + (col ^ ((row & 7) << 4));
}

// lgkm-only barrier: orders LDS writes across the wg WITHOUT draining vmcnt,
// so prefetched global weight loads stay in flight across it (T3/T4).
__device__ __forceinline__ void lds_barrier() {
    asm volatile("s_waitcnt lgkmcnt(0)" ::: "memory");
    __builtin_amdgcn_s_barrier();
    asm volatile("" ::: "memory");
}

__device__ __forceinline__ void load_bq(half8 bq[4], const _Float16* __restrict__ Wq,
                                        int KC, int kc, int w, int lane)
{
    #pragma unroll
    for (int g = 0; g < 4; ++g)
        bq[g] = *(const half8*)(Wq + (((g * 8 + w) * KC + kc) * 64 + lane) * 8);
}

template<int SRC>   // 0 = A0 (stride 72 halfs), 1 = swizzled H tile
__device__ __forceinline__ void load_a(half8 a[4], const char* base, int kc, int c, int q)
{
    #pragma unroll
    for (int mt = 0; mt < 4; ++mt) {
        if (SRC == 0)
            a[mt] = *(const half8*)((const _Float16*)base + (mt * 16 + c) * 72 + kc * 32 + q * 8);
        else
            a[mt] = *(const half8*)(base + swz(mt * 16 + c, kc * 64 + q * 16));
    }
}

// One gemm stage with a 2-DEEP bq ring. On entry bq[0]=this stage's kc0,
// bq[1]=kc1 (prefetched 2 iterations ago, possibly across the stage
// boundary / epilogue). At kc we consume bq[kc&1] and issue the load for
// kc+2 into the same slot (compiler renames; peak 3 live quads). Stage
// tails (kc=KC-2, KC-1) prefetch the NEXT stage's kc0,kc1 (stride KCN).
// FIRST: use bv[g] as the MFMA C operand at kc=0 (bias init without v_movs).
template<int KC, int SRC, bool PF, int KCN, bool FIRST>
__device__ __forceinline__ void gemm_pf2(const _Float16* __restrict__ Wq,
                                         const char* Abase,
                                         const _Float16* __restrict__ Wnext,
                                         half8 bq[2][4], const f32x4 bv[4],
                                         int w, int lane, f32x4 acc[4][4])
{
    const int c = lane & 15, q = lane >> 4;
    #pragma unroll
    for (int kc = 0; kc < KC; ++kc) {
        half8 cur[4];
        #pragma unroll
        for (int g = 0; g < 4; ++g) cur[g] = bq[kc & 1][g];
        if (kc + 2 < KC)      load_bq(bq[kc & 1], Wq, KC, kc + 2, w, lane);
        else if (PF)          load_bq(bq[kc & 1], Wnext, KCN, kc + 2 - KC, w, lane);
        half8 a[4];
        load_a<SRC>(a, Abase, kc, c, q);
        __builtin_amdgcn_s_setprio(1);
        #pragma unroll
        for (int mt = 0; mt < 4; ++mt)
            #pragma unroll
            for (int g = 0; g < 4; ++g) {
                f32x4 cin = (FIRST && kc == 0) ? bv[g] : acc[mt][g];
                acc[mt][g] = __builtin_amdgcn_mfma_f32_16x16x32_f16(cur[g], a[mt], cin, 0, 0, 0);
            }
        __builtin_amdgcn_s_setprio(0);
    }
}

__global__ __launch_bounds__(512) void lstm_main(
    const float* __restrict__ x, const _Float16* __restrict__ Wp_in,
    const float* __restrict__ bias0f_in, const float* __restrict__ bias1f_in,
    const float* __restrict__ mu_g2_in, const float* __restrict__ fc_w_in,
    const float* __restrict__ fc_b_in, float* __restrict__ out)
{
    // LDS 49152 B:
    //  [0, 16384)       H1s   (swizzled [64][256B])
    //  [16384, 32768)   H2s   -- ALSO hosts A0 (64 x 72 halfs = 9216 B):
    //                      A0 dead at S1-barrier; H2s first written in epi2.
    //  [32768, 49152)   H11s
    __shared__ __align__(16) char smem[49152];
    char* H1s  = smem;
    char* H2s  = smem + 16384;
    char* H11s = smem + 32768;
    _Float16* A0 = (_Float16*)(smem + 16384);    // alias of H2s region

    const int t = threadIdx.x;
    const int w = t >> 6, lane = t & 63, c = lane & 15, q = lane >> 4;
    const int wg = blockIdx.x;                   // 1024 wgs x 64 rows
    const int b = wg >> 4;                       // 16 wgs (1024 rows) per batch
    const int bq_idx = w * 4 + q;                // float4 index of (w,q) slice

    // ---- preload S1 kc0 + kc1 weights with maximum lead -------------------
    half8 bq[2][4];
    load_bq(bq[0], Wp_in + WP_WIH0, 2, 0, w, lane);
    load_bq(bq[1], Wp_in + WP_WIH0, 2, 1, w, lane);

    // ---- preamble: stage x tile into A0 (coalesced); init out rows --------
    {
        const float* xp = x + (size_t)wg * 4096 + t * 8;
        float4 u0 = ((const float4*)xp)[0];
        float4 u1 = ((const float4*)xp)[1];
        half8 hv;
        hv[0] = (_Float16)u0.x; hv[1] = (_Float16)u0.y;
        hv[2] = (_Float16)u0.z; hv[3] = (_Float16)u0.w;
        hv[4] = (_Float16)u1.x; hv[5] = (_Float16)u1.y;
        hv[6] = (_Float16)u1.z; hv[7] = (_Float16)u1.w;
        *(half8*)(A0 + (t >> 3) * 72 + (t & 7) * 8) = hv;
        if (t < 64) out[(size_t)wg * 64 + t] = fc_b_in[0];
    }
    lds_barrier();   // A0 visible (lgkm); weight preloads still in flight

    f32x4 acc[4][4];
    float cc[4][4];

    // ---- S1: layer0 step1 (A from A0; bias0 as MFMA C) --------------------
    // Tails prefetch Whh0 kc0+kc1.
    {
        f32x4 bv[4];
        {
            const float* bias0f = bias0f_in; asm volatile("" : "+s"(bias0f));
            #pragma unroll
            for (int g = 0; g < 4; ++g)
                bv[g] = ((const f32x4*)bias0f)[g * 32 + bq_idx];
        }
        gemm_pf2<2, 0, true, 4, true>(Wp_in + WP_WIH0, (const char*)A0,
                                      Wp_in + WP_WHH0, bq, bv, w, lane, acc);
    }
    #pragma unroll
    for (int mt = 0; mt < 4; ++mt) {
        half4_t hv;
        #pragma unroll
        for (int r = 0; r < 4; ++r) {
            float c1 = sig2(acc[mt][0][r]) * tanh2(acc[mt][2][r]);
            cc[mt][r] = c1;
            hv[r] = (_Float16)(sig2(acc[mt][3][r]) * tanh2(c1 * L2E2));
        }
        *(half4_t*)(H1s + swz(mt * 16 + c, w * 32 + q * 8)) = hv;
    }
    lds_barrier();   // [S1-barrier] H1s ready; A0 dead; Whh0 kc0/kc1 in flight

    // ---- S2: layer0 step2 (A from H1s; mu_g2 as MFMA C) -------------------
    // Tails prefetch Wih1 kc0+kc1.
    {
        f32x4 bv[4];
        {
            const float* mu_g2b = mu_g2_in + b * 512; asm volatile("" : "+s"(mu_g2b));
            #pragma unroll
            for (int g = 0; g < 4; ++g)
                bv[g] = ((const f32x4*)mu_g2b)[g * 32 + bq_idx];
        }
        gemm_pf2<4, 1, true, 4, true>(Wp_in + WP_WHH0, H1s,
                                      Wp_in + WP_WIH1, bq, bv, w, lane, acc);
    }
    // epi2: h2 -> H2s (overwrites dead A0; no barrier: S3 reads only H1s)
    #pragma unroll
    for (int mt = 0; mt < 4; ++mt) {
        half4_t hv;
        #pragma unroll
        for (int r = 0; r < 4; ++r) {
            float c2 = sig2(acc[mt][1][r]) * cc[mt][r]
                     + sig2(acc[mt][0][r]) * tanh2(acc[mt][2][r]);
            hv[r] = (_Float16)(sig2(acc[mt][3][r]) * tanh2(c2 * L2E2));
        }
        *(half4_t*)(H2s + swz(mt * 16 + c, w * 32 + q * 8)) = hv;
    }

    // ---- S3: layer1 step1 (A from H1s; bias1 as MFMA C) -------------------
    // Tails prefetch Wih1 kc0+kc1 AGAIN (S4a uses the same matrix; L2-hot).
    {
        f32x4 bv[4];
        {
            const float* bias1f = bias1f_in; asm volatile("" : "+s"(bias1f));
            #pragma unroll
            for (int g = 0; g < 4; ++g)
                bv[g] = ((const f32x4*)bias1f)[g * 32 + bq_idx];
        }
        gemm_pf2<4, 1, true, 4, true>(Wp_in + WP_WIH1, H1s,
                                      Wp_in + WP_WIH1, bq, bv, w, lane, acc);
    }
    // epi3: h11 -> H11s, cc := layer-1 c1
    #pragma unroll
    for (int mt = 0; mt < 4; ++mt) {
        half4_t hv;
        #pragma unroll
        for (int r = 0; r < 4; ++r) {
            float c1 = sig2(acc[mt][0][r]) * tanh2(acc[mt][2][r]);
            cc[mt][r] = c1;
            hv[r] = (_Float16)(sig2(acc[mt][3][r]) * tanh2(c1 * L2E2));
        }
        *(half4_t*)(H11s + swz(mt * 16 + c, w * 32 + q * 8)) = hv;
    }
    lds_barrier();   // [S3-barrier] H2s + H11s ready; Wih1 kc0/kc1 in flight

    // ---- S4: layer1 step2 (Wih1@H2s + Whh1@H11s; bias1 as MFMA C) ---------
    // S4a tails prefetch Whh1 kc0+kc1; S4b has no prefetch.
    {
        f32x4 bv[4];
        {
            const float* bias1f = bias1f_in; asm volatile("" : "+s"(bias1f));
            #pragma unroll
            for (int g = 0; g < 4; ++g)
                bv[g] = ((const f32x4*)bias1f)[g * 32 + bq_idx];
        }
        gemm_pf2<4, 1, true, 4, true>(Wp_in + WP_WIH1, H2s,
                                      Wp_in + WP_WHH1, bq, bv, w, lane, acc);
    }
    gemm_pf2<4, 1, false, 4, false>(Wp_in + WP_WHH1, H11s,
                                    nullptr, bq, nullptr, w, lane, acc);

    // epilogue: h2_1 -> relu -> dot fc_w; partials straight to L2 atomics
    // (out pre-inited with fc_b in preamble; only this wg touches these 64
    //  rows; the store retires during the intervening vmcnt traffic).
    {
        const float* fc_w = fc_w_in; asm volatile("" : "+s"(fc_w));
        f32x4 fwv = ((const f32x4*)fc_w)[bq_idx];
        #pragma unroll
        for (int mt = 0; mt < 4; ++mt) {
            float v = 0.0f;
            #pragma unroll
            for (int r = 0; r < 4; ++r) {
                float c2 = sig2(acc[mt][1][r]) * cc[mt][r]
                         + sig2(acc[mt][0][r]) * tanh2(acc[mt][2][r]);
                float h  = sig2(acc[mt][3][r]) * tanh2(c2 * L2E2);
                v = fmaf(fmaxf(h, 0.0f), fwv[r], v);
            }
            v += __shfl_xor(v, 16);
            v += __shfl_xor(v, 32);
            if (lane < 16)
                atomicAdd(out + (size_t)wg * 64 + mt * 16 + lane, v);
        }
    }
}

extern "C" void kernel_launch(void* const* d_in, const int* in_sizes, int n_in,
                              void* d_out, int out_size, void* d_ws, size_t ws_size,
                              hipStream_t stream)
{
    const float* x    = (const float*)d_in[0];
    const float* mu   = (const float*)d_in[1];
    const float* Wih0 = (const float*)d_in[2];
    const float* Whh0 = (const float*)d_in[3];
    const float* bih0 = (const float*)d_in[4];
    const float* bhh0 = (const float*)d_in[5];
    const float* Wih1 = (const float*)d_in[6];
    const float* Whh1 = (const float*)d_in[7];
    const float* bih1 = (const float*)d_in[8];
    const float* bhh1 = (const float*)d_in[9];
    const float* fcw  = (const float*)d_in[10];
    const float* fcb  = (const float*)d_in[11];
    float* out = (float*)d_out;

    _Float16* Wp  = (_Float16*)d_ws;
    float* bias0f = (float*)((char*)d_ws + WS_BIAS0);
    float* bias1f = (float*)((char*)d_ws + WS_BIAS1);
    float* mu_g2  = (float*)((char*)d_ws + WS_MUG2);

    hipLaunchKernelGGL(prep_kernel, dim3(241), dim3(256), 0, stream,
                       Wih0, Whh0, Wih1, Whh1, bih0, bhh0, bih1, bhh1, mu,
                       Wp, bias0f, bias1f, mu_g2);
    hipLaunchKernelGGL(lstm_main, dim3(1024), dim3(512), 0, stream,
                       x, Wp, bias0f, bias1f, mu_g2, fcw, fcb, out);
}